// Round 1
// baseline (66.158 us; speedup 1.0000x reference)
//
#include <hip/hip_runtime.h>
#include <hip/hip_bf16.h>

// Problem: B=1024, IN_F=256, OUT_F=128, AGG=4
//   z[b,j]  = max_i min(m[b,i], W[i,j]),  j in [0, 512)
//   out[b,o]= max_{a<4} z[b, o*4+a]
// Identity: max_a min(x, w_a) = min(x, max_a w_a)
//   => out[b,o] = max_i min(m[b,i], Wmax[i,o]),  Wmax[i,o] = max_a W[i, o*4+a]
// Kernel 1 folds AGG into Wmax (k-packed layout for coalesced x4 loads).
// Kernel 2 is a max-min GEMM: wave spans o (64 lanes), b wave-uniform.

#define B_DIM 1024
#define K_DIM 256
#define O_DIM 128

// Wmax packed layout: element (k, o) at wpk[(k>>2)*O_DIM*4 + o*4 + (k&3)]
// -> a lane with fixed o reads k..k+3 as one float4 at ((k>>2)*O_DIM + o)*4.

__global__ __launch_bounds__(256) void agg_fold_kernel(
    const float* __restrict__ w, float* __restrict__ wpk) {
  const int t = blockIdx.x * 256 + threadIdx.x;  // 0 .. 32767
  const int k = t >> 7;                          // 0 .. 255
  const int o = t & 127;                         // 0 .. 127
  const float4 v = *(const float4*)(w + (size_t)k * 512 + o * 4);
  const float mx = fmaxf(fmaxf(v.x, v.y), fmaxf(v.z, v.w));
  wpk[((k >> 2) * O_DIM + o) * 4 + (k & 3)] = mx;
}

__global__ __launch_bounds__(256) void tropical_kernel(
    const float* __restrict__ m, const float* __restrict__ wpk,
    float* __restrict__ out) {
  const int tid = threadIdx.x;
  const int o = tid & 127;        // wave0: o 0..63, wave1: o 64..127
  const int ty = tid >> 7;        // wave-uniform: 0 for waves 0/1, 1 for 2/3
  int b0 = blockIdx.x * 4 + ty * 2;
  b0 = __builtin_amdgcn_readfirstlane(b0);  // force SGPR -> scalar m loads

  const float* mr0 = m + (size_t)b0 * K_DIM;
  const float* mr1 = mr0 + K_DIM;
  const float* wp = wpk + o * 4;

  float acc0 = -3.402823466e38f;
  float acc1 = -3.402823466e38f;

#pragma unroll 4
  for (int k = 0; k < K_DIM; k += 8) {
    const float4 w0 = *(const float4*)(wp + (k >> 2) * (O_DIM * 4));
    const float4 w1 = *(const float4*)(wp + (k >> 2) * (O_DIM * 4) + O_DIM * 4);
    const float4 a0 = *(const float4*)(mr0 + k);
    const float4 a1 = *(const float4*)(mr0 + k + 4);
    const float4 c0 = *(const float4*)(mr1 + k);
    const float4 c1 = *(const float4*)(mr1 + k + 4);
    // nested fmaxf so clang can fuse to v_max3_f32
    acc0 = fmaxf(acc0, fmaxf(fminf(a0.x, w0.x), fminf(a0.y, w0.y)));
    acc0 = fmaxf(acc0, fmaxf(fminf(a0.z, w0.z), fminf(a0.w, w0.w)));
    acc0 = fmaxf(acc0, fmaxf(fminf(a1.x, w1.x), fminf(a1.y, w1.y)));
    acc0 = fmaxf(acc0, fmaxf(fminf(a1.z, w1.z), fminf(a1.w, w1.w)));
    acc1 = fmaxf(acc1, fmaxf(fminf(c0.x, w0.x), fminf(c0.y, w0.y)));
    acc1 = fmaxf(acc1, fmaxf(fminf(c0.z, w0.z), fminf(c0.w, w0.w)));
    acc1 = fmaxf(acc1, fmaxf(fminf(c1.x, w1.x), fminf(c1.y, w1.y)));
    acc1 = fmaxf(acc1, fmaxf(fminf(c1.z, w1.z), fminf(c1.w, w1.w)));
  }

  out[(size_t)b0 * O_DIM + o] = acc0;
  out[(size_t)b0 * O_DIM + O_DIM + o] = acc1;
}

extern "C" void kernel_launch(void* const* d_in, const int* in_sizes, int n_in,
                              void* d_out, int out_size, void* d_ws, size_t ws_size,
                              hipStream_t stream) {
  const float* m = (const float*)d_in[0];       // [1024, 256]
  const float* w = (const float*)d_in[1];       // [256, 512]
  float* wpk = (float*)d_ws;                    // [64][128][4] = 128 KB
  float* out = (float*)d_out;                   // [1024, 128]

  // Kernel 1: fold AGG into weight, 32768 elements
  agg_fold_kernel<<<(K_DIM * O_DIM) / 256, 256, 0, stream>>>(w, wpk);

  // Kernel 2: max-min GEMM, 4 b-rows per block (2 per wave-pair, T_B=2)
  tropical_kernel<<<B_DIM / 4, 256, 0, stream>>>(m, wpk, out);
}

// Round 2
// 64.330 us; speedup vs baseline: 1.0284x; 1.0284x over previous
//
#include <hip/hip_runtime.h>
#include <hip/hip_bf16.h>

// Problem: B=1024, IN_F=256, OUT_F=128, AGG=4
//   out[b,o] = max_i min(m[b,i], Wmax[i,o]),  Wmax[i,o] = max_a W[i, o*4+a]
//   (identity: max_a min(x,w_a) = min(x, max_a w_a) — exact in fp32)
// Kernel 1: fold AGG into Wmax, k-packed [k/4][o][4] for float4 loads.
// Kernel 2: max-min GEMM. Block = 4 b-rows x 128 o x 2 k-halves.
//   tid: o = tid&127, kh = tid>>7 (wave-uniform). T_B=4 accs/thread.
//   L2 weight traffic: 1024 waves x 32 KB = 32 MB (~1 us at 34.5 TB/s).

#define B_DIM 1024
#define K_DIM 256
#define O_DIM 128

__global__ __launch_bounds__(256) void agg_fold_kernel(
    const float* __restrict__ w, float* __restrict__ wpk) {
  const int t = blockIdx.x * 256 + threadIdx.x;  // 0 .. 32767
  const int k = t >> 7;                          // 0 .. 255
  const int o = t & 127;                         // 0 .. 127
  const float4 v = *(const float4*)(w + (size_t)k * 512 + o * 4);
  const float mx = fmaxf(fmaxf(v.x, v.y), fmaxf(v.z, v.w));
  wpk[((k >> 2) * O_DIM + o) * 4 + (k & 3)] = mx;
}

#define NEG_INF (-3.402823466e38f)

__global__ __launch_bounds__(256) void tropical_kernel(
    const float* __restrict__ m, const float* __restrict__ wpk,
    float* __restrict__ out) {
  __shared__ float comb[O_DIM * 4];  // kh=1 partials, 2 KB

  const int tid = threadIdx.x;
  const int o = tid & 127;
  const int kh = tid >> 7;  // wave-uniform: waves 0,1 -> 0; waves 2,3 -> 1
  int b0 = blockIdx.x * 4;
  b0 = __builtin_amdgcn_readfirstlane(b0);
  const int k0 = __builtin_amdgcn_readfirstlane(kh << 7);  // 0 or 128

  const float* mrow = m + (size_t)b0 * K_DIM + k0;         // rows b0..b0+3
  const float* wp = wpk + (size_t)(k0 >> 2) * (O_DIM * 4) + o * 4;

  float a0 = NEG_INF, a1 = NEG_INF, a2 = NEG_INF, a3 = NEG_INF;

#pragma unroll 4
  for (int g = 0; g < 32; ++g) {  // 4 k per group, 128 k per thread
    const float4 w = *(const float4*)(wp + g * (O_DIM * 4));
    const float4 m0 = *(const float4*)(mrow + g * 4);
    const float4 m1 = *(const float4*)(mrow + K_DIM + g * 4);
    const float4 m2 = *(const float4*)(mrow + 2 * K_DIM + g * 4);
    const float4 m3 = *(const float4*)(mrow + 3 * K_DIM + g * 4);
    a0 = fmaxf(a0, fmaxf(fmaxf(fminf(m0.x, w.x), fminf(m0.y, w.y)),
                         fmaxf(fminf(m0.z, w.z), fminf(m0.w, w.w))));
    a1 = fmaxf(a1, fmaxf(fmaxf(fminf(m1.x, w.x), fminf(m1.y, w.y)),
                         fmaxf(fminf(m1.z, w.z), fminf(m1.w, w.w))));
    a2 = fmaxf(a2, fmaxf(fmaxf(fminf(m2.x, w.x), fminf(m2.y, w.y)),
                         fmaxf(fminf(m2.z, w.z), fminf(m2.w, w.w))));
    a3 = fmaxf(a3, fmaxf(fmaxf(fminf(m3.x, w.x), fminf(m3.y, w.y)),
                         fmaxf(fminf(m3.z, w.z), fminf(m3.w, w.w))));
  }

  if (kh) {
    *(float4*)&comb[o * 4] = make_float4(a0, a1, a2, a3);
  }
  __syncthreads();
  if (!kh) {
    const float4 c = *(const float4*)&comb[o * 4];
    out[(size_t)(b0 + 0) * O_DIM + o] = fmaxf(a0, c.x);
    out[(size_t)(b0 + 1) * O_DIM + o] = fmaxf(a1, c.y);
    out[(size_t)(b0 + 2) * O_DIM + o] = fmaxf(a2, c.z);
    out[(size_t)(b0 + 3) * O_DIM + o] = fmaxf(a3, c.w);
  }
}

extern "C" void kernel_launch(void* const* d_in, const int* in_sizes, int n_in,
                              void* d_out, int out_size, void* d_ws, size_t ws_size,
                              hipStream_t stream) {
  const float* m = (const float*)d_in[0];  // [1024, 256]
  const float* w = (const float*)d_in[1];  // [256, 512]
  float* wpk = (float*)d_ws;               // [64][128][4] = 128 KB
  float* out = (float*)d_out;              // [1024, 128]

  agg_fold_kernel<<<(K_DIM * O_DIM) / 256, 256, 0, stream>>>(w, wpk);
  tropical_kernel<<<B_DIM / 4, 256, 0, stream>>>(m, wpk, out);
}